// Round 1
// baseline (388.141 us; speedup 1.0000x reference)
//
#include <hip/hip_runtime.h>
#include <hip/hip_bf16.h>

// y[b,f,c] = sum_hw x[b,c,hw] * k[f,c,hw];  out[b, f*C + c]
// B=256, F=16, C=256, HW=1024, fp32.
//
// R4 lesson: no waves-per-eu hint (caps allocator -> loop spills).
// R6 lesson: RB=4 + NT regressed; RB stays 2.
// R7: stage ALL of K[.,c,.] (64 KB LDS) once at kernel start; main loop is
// barrier-free so the x-stream (268 MB, sets the HBM floor) never stalls.
// R8 (this round): kernel dispatch is ~64us (bench dur includes ~318us of
// harness poison fills; sle_kernel absent from rocprof top-5 => <158us).
//  (a) BT=64 / 512 threads: same 64 KiB LDS, still 2 blocks/CU, but
//      16 waves/CU (50%) instead of 8 (25%) -> 2x in-flight x loads.
//  (b) XCD swizzle: c = (g&7)*32 + ((g>>3)&31), btile = g>>8. Same-c
//      blocks share blockIdx%8 (same XCD), each XCD owns a contiguous
//      32-c chunk (2 MB K < 4 MB L2) -> K fetched ~once, not 8x; output
//      lines (16 c's per 64B) merge within one XCD's L2.

constexpr int Bb = 256;
constexpr int Ff = 16;
constexpr int Cc = 256;
constexpr int HW = 1024;
constexpr int CHW = Cc * HW;

constexpr int BT = 64;             // b per block (R8: was 32)
constexpr int RB = 2;              // b per thread
constexpr int NTHREADS = (BT / RB) * 16;   // 512
constexpr int NJ = HW / 4 / 16;    // 16 j-iters (whole hw range)

__device__ __forceinline__ float dot4(float4 a, float4 b) {
    return a.x * b.x + a.y * b.y + a.z * b.z + a.w * b.w;
}
__device__ __forceinline__ float red16(float v) {
    v += __shfl_xor(v, 1);
    v += __shfl_xor(v, 2);
    v += __shfl_xor(v, 4);
    v += __shfl_xor(v, 8);
    return v;
}

__global__ __launch_bounds__(NTHREADS)   // no waves-per-eu hint (R4 lesson)
void sle_kernel(const float* __restrict__ x, const float* __restrict__ k,
                float* __restrict__ out) {
    __shared__ float ldsK[Ff * HW];           // 64 KiB: whole K for this c

    const int t   = threadIdx.x;
    const int thw = t & 15;                   // hw split within 16-lane group
    const int tbg = t >> 4;                   // 0..31, b group

    // ---- XCD-aware decode of (c, btile) from blockIdx (R8b) ----
    const int g     = blockIdx.x;
    const int c     = (g & 7) * 32 + ((g >> 3) & 31);  // XCD owns 32-c chunk
    const int btile = g >> 8;                 // 0..3; same-c blocks: g%8 equal
    const int b0    = btile * BT + tbg * RB;

    // ---- stage K[f][0..HW) for this c: 16384 floats, 8 float4/thread ----
    {
        const int fr = t >> 5, lane32 = t & 31;   // 32 threads per f-row
        const float4* src = (const float4*)(k + (size_t)fr * CHW + (size_t)c * HW);
        float4* dst = (float4*)(ldsK + fr * HW);
#pragma unroll
        for (int q = 0; q < 8; ++q)
            dst[lane32 + 32 * q] = src[lane32 + 32 * q];
    }
    __syncthreads();

    const float* x0 = x + (size_t)(b0 + 0) * CHW + (size_t)c * HW;
    const float* x1 = x + (size_t)(b0 + 1) * CHW + (size_t)c * HW;

    float4 a00 = {0,0,0,0}, a01 = {0,0,0,0}, a02 = {0,0,0,0}, a03 = {0,0,0,0};
    float4 a10 = {0,0,0,0}, a11 = {0,0,0,0}, a12 = {0,0,0,0}, a13 = {0,0,0,0};

    // ---- barrier-free main loop over the whole hw range ----
#pragma unroll 4
    for (int j = 0; j < NJ; ++j) {
        const int f4  = thw + 16 * j;         // float4 index in hw
        const int off = 4 * f4;
        const float4 xv0 = *(const float4*)(x0 + off);
        const float4 xv1 = *(const float4*)(x1 + off);

#define ACC_G(G, A0, A1) {                                              \
        const float* kp = ldsK + (4 * (G)) * HW + off;                  \
        const float4 k0 = *(const float4*)(kp);                         \
        const float4 k1 = *(const float4*)(kp + HW);                    \
        const float4 k2 = *(const float4*)(kp + 2 * HW);                \
        const float4 k3 = *(const float4*)(kp + 3 * HW);                \
        A0.x += dot4(xv0, k0); A0.y += dot4(xv0, k1);                   \
        A0.z += dot4(xv0, k2); A0.w += dot4(xv0, k3);                   \
        A1.x += dot4(xv1, k0); A1.y += dot4(xv1, k1);                   \
        A1.z += dot4(xv1, k2); A1.w += dot4(xv1, k3); }

        ACC_G(0, a00, a10)
        ACC_G(1, a01, a11)
        ACC_G(2, a02, a12)
        ACC_G(3, a03, a13)
#undef ACC_G
    }

    // reduce the 16 hw-split lanes; all lanes valid (butterfly)
#define RED4(A) { A.x = red16(A.x); A.y = red16(A.y); \
                  A.z = red16(A.z); A.w = red16(A.w); }
    RED4(a00) RED4(a01) RED4(a02) RED4(a03)
    RED4(a10) RED4(a11) RED4(a12) RED4(a13)
#undef RED4

    __syncthreads();                          // done reading ldsK as K-tile
    if (thw == 0) {
        float4* row0 = (float4*)(ldsK + (tbg * RB + 0) * Ff);
        float4* row1 = (float4*)(ldsK + (tbg * RB + 1) * Ff);
        row0[0] = a00; row0[1] = a01; row0[2] = a02; row0[3] = a03;
        row1[0] = a10; row1[1] = a11; row1[2] = a12; row1[3] = a13;
    }
    __syncthreads();

    // 1024 results (64 b x 16 f); 2 dword stores per thread
#pragma unroll
    for (int i = 0; i < (BT * Ff) / NTHREADS; ++i) {   // 2
        const int idx = t + NTHREADS * i;              // 0..1023
        const int bl  = idx >> 4;
        const int f   = idx & 15;
        out[(size_t)(btile * BT + bl) * (Ff * Cc) + f * Cc + c] = ldsK[idx];
    }
}

extern "C" void kernel_launch(void* const* d_in, const int* in_sizes, int n_in,
                              void* d_out, int out_size, void* d_ws, size_t ws_size,
                              hipStream_t stream) {
    const float* x = (const float*)d_in[0];
    const float* k = (const float*)d_in[1];
    float* out = (float*)d_out;
    const int grid = Cc * (Bb / BT);  // 1024
    sle_kernel<<<grid, NTHREADS, 0, stream>>>(x, k, out);
}